// Round 10
// baseline (233.672 us; speedup 1.0000x reference)
//
#include <hip/hip_runtime.h>
#include <math.h>

#define Bdim  2
#define Nseq  2048
#define Dmod  512
#define Hn    8
#define DHd   64
#define HID   2730
#define HHALF 1365
#define HC    1408      // combined hidden, padded (22*64)
#define NPACK 2816      // packed fc1 output cols (2*HC)
#define ROWS  4096      // Bdim*Nseq
#define NSPLIT 2        // attention split-K

typedef __bf16    bf16x8 __attribute__((ext_vector_type(8)));
typedef __bf16    bf16x4 __attribute__((ext_vector_type(4)));
typedef float     f32x4  __attribute__((ext_vector_type(4)));
typedef _Float16  f16x8  __attribute__((ext_vector_type(8)));
typedef _Float16  f16x4  __attribute__((ext_vector_type(4)));

__device__ __forceinline__ void glds16(const __bf16* g, __bf16* l) {
    __builtin_amdgcn_global_load_lds(
        (const __attribute__((address_space(1))) void*)g,
        (__attribute__((address_space(3))) void*)l, 16, 0, 0);
}

// ---------------- LN body (shared) ----------------
__device__ __forceinline__ void ln_body(
    int row, int tid, const float* __restrict__ x, const float* __restrict__ w,
    const float* __restrict__ b, __bf16* __restrict__ out)
{
    const float* xr = x + (size_t)row * Dmod;
    float2 v = *(const float2*)(xr + tid * 2);
    float s  = v.x + v.y;
    float sq = v.x * v.x + v.y * v.y;
#pragma unroll
    for (int m = 1; m < 64; m <<= 1) {
        s  += __shfl_xor(s, m, 64);
        sq += __shfl_xor(sq, m, 64);
    }
    __shared__ float ss[4], ssq[4];
    const int wv = tid >> 6;
    if ((tid & 63) == 0) { ss[wv] = s; ssq[wv] = sq; }
    __syncthreads();
    s  = ss[0] + ss[1] + ss[2] + ss[3];
    sq = ssq[0] + ssq[1] + ssq[2] + ssq[3];
    const float mean = s * (1.0f / Dmod);
    const float var  = sq * (1.0f / Dmod) - mean * mean;
    const float rstd = rsqrtf(var + 1e-5f);
    float2 wv2 = *(const float2*)(w + tid * 2);
    float2 bv2 = *(const float2*)(b + tid * 2);
    __bf16* orow = out + (size_t)row * Dmod + tid * 2;
    orow[0] = (__bf16)((v.x - mean) * rstd * wv2.x + bv2.x);
    orow[1] = (__bf16)((v.y - mean) * rstd * wv2.y + bv2.y);
}

// ---------------- fused weight conversion + LN1 + dist precompute ----------------
#define SEG0 (1536*512)
#define SEG1 (512*512)
#define SEG2 (NPACK*512)
#define SEG3 (512*HC)
#define CONV_BLOCKS ((SEG0 + SEG1 + SEG2 + SEG3) / 256)
#define DIST_BLOCKS (Bdim * Nseq * Nseq / 256)   // 32768
__global__ __launch_bounds__(256) void convert_ln(
    const float* __restrict__ q_w, const float* __restrict__ k_w,
    const float* __restrict__ v_w, const float* __restrict__ o_w,
    const float* __restrict__ fc1_w, const float* __restrict__ fc2_w,
    __bf16* __restrict__ wqkv, __bf16* __restrict__ wo,
    __bf16* __restrict__ wfc1p, __bf16* __restrict__ wfc2p,
    const float* __restrict__ x, const float* __restrict__ ln1w,
    const float* __restrict__ ln1b, __bf16* __restrict__ xn,
    const float* __restrict__ coords, _Float16* __restrict__ db)
{
    if (blockIdx.x >= CONV_BLOCKS + ROWS) {
        // dist[b][q][k] = |coords[b,q] - coords[b,k]| (fp16, head-independent)
        int idx = (blockIdx.x - CONV_BLOCKS - ROWS) * 256 + threadIdx.x;
        int b = idx >> 22;
        int rem = idx & ((1 << 22) - 1);
        int q = rem >> 11, k = rem & 2047;
        float2 cq = *(const float2*)(coords + ((size_t)b * Nseq + q) * 2);
        float2 ck = *(const float2*)(coords + ((size_t)b * Nseq + k) * 2);
        float dx = cq.x - ck.x, dy = cq.y - ck.y;
        db[idx] = (_Float16)__builtin_amdgcn_sqrtf(dx * dx + dy * dy);
        return;
    }
    if (blockIdx.x >= CONV_BLOCKS) {
        ln_body(blockIdx.x - CONV_BLOCKS, threadIdx.x, x, ln1w, ln1b, xn);
        return;
    }
    int idx = blockIdx.x * 256 + threadIdx.x;
    if (idx < SEG0) {
        int n = idx >> 9, k = idx & 511;
        float v = (n < 512) ? q_w[n * 512 + k]
                : (n < 1024) ? k_w[(n - 512) * 512 + k]
                : v_w[(n - 1024) * 512 + k];
        wqkv[idx] = (__bf16)v;
        return;
    }
    idx -= SEG0;
    if (idx < SEG1) { wo[idx] = (__bf16)o_w[idx]; return; }
    idx -= SEG1;
    if (idx < SEG2) {
        int n = idx >> 9, k = idx & 511;
        int j = n >> 5, u = n & 31;
        int base = j * 16 + (u & 15);
        float v = 0.0f;
        if (base < HHALF) {
            int hidx = base + ((u & 16) ? HHALF : 0);
            v = fc1_w[(size_t)hidx * 512 + k];
        }
        wfc1p[idx] = (__bf16)v;
        return;
    }
    idx -= SEG2;
    if (idx < SEG3) {
        int n = idx / HC, k = idx - n * HC;
        float v = (k < HHALF) ? fc2_w[(size_t)n * HHALF + k] : 0.0f;
        wfc2p[idx] = (__bf16)v;
    }
}

// ---------------- LN2 ----------------
__global__ __launch_bounds__(256) void ln_kernel(
    const float* __restrict__ x, const float* __restrict__ w,
    const float* __restrict__ b, __bf16* __restrict__ out)
{
    ln_body(blockIdx.x, threadIdx.x, x, w, b, out);
}

// ---------------- 64x64 residual GEMM, 8 waves, K-parallel x2, XOR-swizzled LDS ----------------
__global__ __launch_bounds__(512) void gemm_res(
    const __bf16* __restrict__ A, int lda,
    const __bf16* __restrict__ Bw, int ldb,
    const float* __restrict__ bias, int K,
    float* __restrict__ out_f32, int ld_out,
    const float* __restrict__ res, const float* __restrict__ g)
{
    __shared__ __bf16 smem[2 * 64 * 64];
    __bf16* As = smem;
    __bf16* Bs = smem + 64 * 64;
    const int tid  = threadIdx.x;
    const int wave = tid >> 6, lane = tid & 63;
    const int t    = lane & 15, quad = lane >> 4;
    const int kg   = wave >> 2, wv = wave & 3;
    const int m0   = blockIdx.x * 64;
    const int n0   = blockIdx.y * 64;

    const int srow = tid >> 3;
    const int gch  = ((tid & 7) ^ (srow & 7)) * 8;
    const __bf16* aptr = A  + (size_t)(m0 + srow) * lda + gch;
    const __bf16* bptr = Bw + (size_t)(n0 + srow) * ldb + gch;

    const int arow = wv * 16 + t;
    const int aoff = arow * 64 + (((kg * 4 + quad) ^ (arow & 7)) * 8);
    int boffs[4];
#pragma unroll
    for (int ct = 0; ct < 4; ++ct) {
        int brow = ct * 16 + t;
        boffs[ct] = brow * 64 + (((kg * 4 + quad) ^ (brow & 7)) * 8);
    }

    f32x4 acc[4] = {};
    for (int k0 = 0; k0 < K; k0 += 64) {
        __syncthreads();
        glds16(aptr + k0, As + tid * 8);
        glds16(bptr + k0, Bs + tid * 8);
        __syncthreads();
        bf16x8 a = *(const bf16x8*)(As + aoff);
#pragma unroll
        for (int ct = 0; ct < 4; ++ct) {
            bf16x8 b = *(const bf16x8*)(Bs + boffs[ct]);
            acc[ct] = __builtin_amdgcn_mfma_f32_16x16x32_bf16(a, b, acc[ct], 0, 0, 0);
        }
    }

    __syncthreads();
    if (kg == 1) {
        float* dst = (float*)smem + ((size_t)wv * 64 + lane) * 16;
#pragma unroll
        for (int ct = 0; ct < 4; ++ct) *(f32x4*)(dst + ct * 4) = acc[ct];
    }
    __syncthreads();
    if (kg == 0) {
        const float* src = (const float*)smem + ((size_t)wv * 64 + lane) * 16;
        const int row_base = m0 + wv * 16 + quad * 4;
#pragma unroll
        for (int ct = 0; ct < 4; ++ct) {
            f32x4 other = *(const f32x4*)(src + ct * 4);
            const int col = n0 + ct * 16 + t;
            const float bb = bias[col];
#pragma unroll
            for (int r = 0; r < 4; ++r) {
                const int row = row_base + r;
                out_f32[(size_t)row * ld_out + col] =
                    res[(size_t)row * ld_out + col] +
                    g[col] * (acc[ct][r] + other[r] + bb);
            }
        }
    }
}

// ---------------- 128x128 QKV GEMM (BK=32); V written transposed via LDS ----------------
#define LDT 136
__global__ __launch_bounds__(256) void qkv_gemm128(
    const __bf16* __restrict__ A, const __bf16* __restrict__ W,
    const float* __restrict__ qb_, const float* __restrict__ kb_,
    const float* __restrict__ vb_,
    __bf16* __restrict__ qk, __bf16* __restrict__ vtg)
{
    __shared__ __bf16 smem[64 * LDT];
    __bf16* As = smem;
    __bf16* Bs = smem + 4096;
    const int tid  = threadIdx.x;
    const int wave = tid >> 6, lane = tid & 63;
    const int t    = lane & 15, quad = lane >> 4;
    const int m0   = blockIdx.x * 128, n0 = blockIdx.y * 128;
    const int mr   = (wave & 1) * 64,  nr = (wave >> 1) * 64;
    const int ra0 = tid >> 2,          ca0 = (tid & 3) * 8;
    const int ra1 = (tid + 256) >> 2,  ca1 = (tid & 3) * 8;

    f32x4 acc[4][4] = {};

    for (int k0 = 0; k0 < Dmod; k0 += 32) {
        __syncthreads();
        glds16(A + (size_t)(m0 + ra0) * Dmod + k0 + ca0, As + tid * 8);
        glds16(A + (size_t)(m0 + ra1) * Dmod + k0 + ca1, As + (tid + 256) * 8);
        glds16(W + (size_t)(n0 + ra0) * Dmod + k0 + ca0, Bs + tid * 8);
        glds16(W + (size_t)(n0 + ra1) * Dmod + k0 + ca1, Bs + (tid + 256) * 8);
        __syncthreads();
        bf16x8 af[4], bfr[4];
#pragma unroll
        for (int mi = 0; mi < 4; ++mi)
            af[mi] = *(const bf16x8*)(As + (mr + mi * 16 + t) * 32 + quad * 8);
#pragma unroll
        for (int ni = 0; ni < 4; ++ni)
            bfr[ni] = *(const bf16x8*)(Bs + (nr + ni * 16 + t) * 32 + quad * 8);
#pragma unroll
        for (int mi = 0; mi < 4; ++mi)
#pragma unroll
            for (int ni = 0; ni < 4; ++ni)
                acc[mi][ni] = __builtin_amdgcn_mfma_f32_16x16x32_bf16(af[mi], bfr[ni], acc[mi][ni], 0, 0, 0);
    }

    const int y = blockIdx.y;
    if (y < 8) {
#pragma unroll
        for (int mi = 0; mi < 4; ++mi) {
            const int row_base = m0 + mr + mi * 16 + quad * 4;
#pragma unroll
            for (int ni = 0; ni < 4; ++ni) {
                const int col = n0 + nr + ni * 16 + t;
                const float bb = (col < 512) ? qb_[col] : kb_[col - 512];
#pragma unroll
                for (int r = 0; r < 4; ++r)
                    qk[(size_t)(row_base + r) * 1024 + col] = (__bf16)(acc[mi][ni][r] + bb);
            }
        }
    } else {
        const int tok0 = m0 & 2047;
        const int bI   = m0 >> 11;
#pragma unroll
        for (int half = 0; half < 2; ++half) {
            __syncthreads();
            if ((wave >> 1) == half) {
#pragma unroll
                for (int ni = 0; ni < 4; ++ni) {
                    const int dh = ni * 16 + t;
                    const float bb = vb_[(y - 8) * 128 + half * 64 + dh];
#pragma unroll
                    for (int mi = 0; mi < 4; ++mi) {
                        const int n = mr + mi * 16 + quad * 4;
                        bf16x4 pk;
#pragma unroll
                        for (int r = 0; r < 4; ++r) pk[r] = (__bf16)(acc[mi][ni][r] + bb);
                        *(bf16x4*)(smem + dh * LDT + n) = pk;
                    }
                }
            }
            __syncthreads();
            const int hh = (y - 8) * 2 + half;
            const size_t rowbase = (size_t)(bI * 8 + hh) * 64;
#pragma unroll
            for (int j = 0; j < 4; ++j) {
                int chunk = tid + j * 256;
                int dr = chunk >> 4, cc = (chunk & 15) * 8;
                bf16x8 vv = *(const bf16x8*)(smem + dr * LDT + cc);
                *(bf16x8*)(vtg + (rowbase + dr) * Nseq + tok0 + cc) = vv;
            }
        }
    }
}

// ---------------- 128x128 fc1 GEMM (BK=32) with fused SwiGLU epilogue ----------------
__global__ __launch_bounds__(256) void fc1_gemm128(
    const __bf16* __restrict__ A, const __bf16* __restrict__ W,
    const float* __restrict__ fc1_b_, __bf16* __restrict__ out)
{
    __shared__ __bf16 As[128 * 32];
    __shared__ __bf16 Bs[128 * 32];
    const int tid  = threadIdx.x;
    const int wave = tid >> 6, lane = tid & 63;
    const int t    = lane & 15, quad = lane >> 4;
    const int m0   = blockIdx.x * 128, n0 = blockIdx.y * 128;
    const int mr   = (wave & 1) * 64,  nr = (wave >> 1) * 64;
    const int ra0 = tid >> 2,          ca0 = (tid & 3) * 8;
    const int ra1 = (tid + 256) >> 2,  ca1 = (tid & 3) * 8;

    f32x4 acc[4][4] = {};

    for (int k0 = 0; k0 < Dmod; k0 += 32) {
        __syncthreads();
        glds16(A + (size_t)(m0 + ra0) * Dmod + k0 + ca0, As + tid * 8);
        glds16(A + (size_t)(m0 + ra1) * Dmod + k0 + ca1, As + (tid + 256) * 8);
        glds16(W + (size_t)(n0 + ra0) * Dmod + k0 + ca0, Bs + tid * 8);
        glds16(W + (size_t)(n0 + ra1) * Dmod + k0 + ca1, Bs + (tid + 256) * 8);
        __syncthreads();
        bf16x8 af[4], bfr[4];
#pragma unroll
        for (int mi = 0; mi < 4; ++mi)
            af[mi] = *(const bf16x8*)(As + (mr + mi * 16 + t) * 32 + quad * 8);
#pragma unroll
        for (int ni = 0; ni < 4; ++ni)
            bfr[ni] = *(const bf16x8*)(Bs + (nr + ni * 16 + t) * 32 + quad * 8);
#pragma unroll
        for (int mi = 0; mi < 4; ++mi)
#pragma unroll
            for (int ni = 0; ni < 4; ++ni)
                acc[mi][ni] = __builtin_amdgcn_mfma_f32_16x16x32_bf16(af[mi], bfr[ni], acc[mi][ni], 0, 0, 0);
    }

#pragma unroll
    for (int mi = 0; mi < 4; ++mi) {
        const int row_base = m0 + mr + mi * 16 + quad * 4;
#pragma unroll
        for (int gI = 0; gI < 2; ++gI) {
            const int base = n0 + nr + gI * 32;
            const int hb = (base >> 5) * 16 + t;
            const bool valid = hb < HHALF;
            const float b1 = valid ? fc1_b_[hb] : 0.0f;
            const float b2 = valid ? fc1_b_[HHALF + hb] : 0.0f;
#pragma unroll
            for (int r = 0; r < 4; ++r) {
                float a = acc[mi][2 * gI][r] + b1;
                float c = acc[mi][2 * gI + 1][r] + b2;
                float sw = a / (1.0f + __expf(-a)) * c;
                out[(size_t)(row_base + r) * HC + hb] = (__bf16)sw;
            }
        }
    }
}

// ---------------- Flash attention, split-K, no-max softmax, precomputed fp16 dist ----------------
__global__ __launch_bounds__(256) void attn_kernel(
    const __bf16* __restrict__ qk, const __bf16* __restrict__ vt,
    const _Float16* __restrict__ db,
    __bf16* __restrict__ op, float* __restrict__ lp, int ktper)
{
    constexpr int LD = 72;
    __shared__ __bf16 Ks[64][LD];
    __shared__ __bf16 Vt[64][LD];
    __shared__ __bf16 Ps[64][LD];
    __shared__ _Float16 Dds[64 * 64];   // [q][k-chunk XOR-swizzled by q&7]

    const int qt = blockIdx.x, h = blockIdx.y;
    const int s = blockIdx.z >> 1, b = blockIdx.z & 1;
    const int bh = b * Hn + h;
    const int tid = threadIdx.x;
    const int wave = tid >> 6, lane = tid & 63;
    const int t = lane & 15, quad = lane >> 4;
    const float c1 = 0.125f * 1.44269504f;
    const float d1 = exp2f(-(float)(h + 1)) * 1.44269504f;

    const int qrow = qt * 64 + wave * 16 + t;
    const size_t qbase = (size_t)(b * Nseq + qrow) * 1024 + h * DHd;
    bf16x8 bq0 = *(const bf16x8*)(qk + qbase + quad * 8);
    bf16x8 bq1 = *(const bf16x8*)(qk + qbase + 32 + quad * 8);

    const int sr = tid >> 3, scc = (tid & 7) * 8;
    const __bf16* kbase = qk + (size_t)(b * Nseq) * 1024 + 512 + h * DHd;
    const __bf16* vbase = vt + (size_t)(bh * 64) * Nseq;
    // dist staging: row sr (q in tile), swizzled col chunk
    const _Float16* dbase = db + ((size_t)b * Nseq + qt * 64 + sr) * Nseq
                               + ((tid & 7) ^ (sr & 7)) * 8;

    // softmax-read offsets into Dds: lane's q-row in tile = wave*16 + t  [r9 BUG FIX]
    const int qv = wave * 16 + t;
    int doff[4];
#pragma unroll
    for (int am = 0; am < 4; ++am)
        doff[am] = qv * 64 + (((am * 2 + (quad >> 1)) ^ (t & 7)) * 8) + (quad & 1) * 4;

    bf16x8 kreg0, kreg1, vreg0, vreg1;
    f16x8 dreg0, dreg1;
    int kn = s * ktper * 64;
    kreg0 = *(const bf16x8*)(kbase + (size_t)(kn + sr) * 1024 + scc);
    kreg1 = *(const bf16x8*)(kbase + (size_t)(kn + sr + 32) * 1024 + scc);
    vreg0 = *(const bf16x8*)(vbase + (size_t)sr * Nseq + kn + scc);
    vreg1 = *(const bf16x8*)(vbase + (size_t)(sr + 32) * Nseq + kn + scc);
    dreg0 = *(const f16x8*)(dbase + kn);
    dreg1 = *(const f16x8*)(dbase + (size_t)32 * Nseq + kn);

    f32x4 o[4] = {};
    float lrun = 0.0f;

    for (int it = 0; it < ktper; ++it) {
        __syncthreads();
        *(bf16x8*)(&Ks[sr][scc])      = kreg0;
        *(bf16x8*)(&Ks[sr + 32][scc]) = kreg1;
        *(bf16x8*)(&Vt[sr][scc])      = vreg0;
        *(bf16x8*)(&Vt[sr + 32][scc]) = vreg1;
        *(f16x8*)(Dds + tid * 8)         = dreg0;
        *(f16x8*)(Dds + (tid + 256) * 8) = dreg1;
        __syncthreads();
        if (it + 1 < ktper) {
            const int k2 = kn + 64;
            kreg0 = *(const bf16x8*)(kbase + (size_t)(k2 + sr) * 1024 + scc);
            kreg1 = *(const bf16x8*)(kbase + (size_t)(k2 + sr + 32) * 1024 + scc);
            vreg0 = *(const bf16x8*)(vbase + (size_t)sr * Nseq + k2 + scc);
            vreg1 = *(const bf16x8*)(vbase + (size_t)(sr + 32) * Nseq + k2 + scc);
            dreg0 = *(const f16x8*)(dbase + k2);
            dreg1 = *(const f16x8*)(dbase + (size_t)32 * Nseq + k2);
        }

        f32x4 sA[4];
#pragma unroll
        for (int am = 0; am < 4; ++am) {
            bf16x8 a0 = *(const bf16x8*)(&Ks[am * 16 + t][quad * 8]);
            bf16x8 a1 = *(const bf16x8*)(&Ks[am * 16 + t][32 + quad * 8]);
            f32x4 z = {};
            z = __builtin_amdgcn_mfma_f32_16x16x32_bf16(a0, bq0, z, 0, 0, 0);
            sA[am] = __builtin_amdgcn_mfma_f32_16x16x32_bf16(a1, bq1, z, 0, 0, 0);
        }

        float p[4][4];
#pragma unroll
        for (int am = 0; am < 4; ++am) {
            f16x4 dv = *(const f16x4*)(Dds + doff[am]);
#pragma unroll
            for (int r = 0; r < 4; ++r) {
                float e = __builtin_amdgcn_exp2f(sA[am][r] * c1 - d1 * (float)dv[r]);
                p[am][r] = e;
                lrun += e;
            }
        }

#pragma unroll
        for (int am = 0; am < 4; ++am) {
            bf16x4 pk;
#pragma unroll
            for (int r = 0; r < 4; ++r) pk[r] = (__bf16)p[am][r];
            *(bf16x4*)(&Ps[wave * 16 + t][am * 16 + quad * 4]) = pk;
        }

        bf16x8 ap0 = *(const bf16x8*)(&Ps[wave * 16 + t][quad * 8]);
        bf16x8 ap1 = *(const bf16x8*)(&Ps[wave * 16 + t][32 + quad * 8]);
#pragma unroll
        for (int ct = 0; ct < 4; ++ct) {
            bf16x8 bv0 = *(const bf16x8*)(&Vt[ct * 16 + t][quad * 8]);
            bf16x8 bv1 = *(const bf16x8*)(&Vt[ct * 16 + t][32 + quad * 8]);
            o[ct] = __builtin_amdgcn_mfma_f32_16x16x32_bf16(ap0, bv0, o[ct], 0, 0, 0);
            o[ct] = __builtin_amdgcn_mfma_f32_16x16x32_bf16(ap1, bv1, o[ct], 0, 0, 0);
        }
        kn += 64;
    }

    lrun += __shfl_xor(lrun, 16, 64);
    lrun += __shfl_xor(lrun, 32, 64);
    if (quad == 0)
        lp[(((size_t)s * Bdim + b) * Hn + h) * Nseq + qt * 64 + wave * 16 + t] = lrun;

    const int orow_base = qt * 64 + wave * 16 + quad * 4;
#pragma unroll
    for (int ct = 0; ct < 4; ++ct)
#pragma unroll
        for (int r = 0; r < 4; ++r) {
            size_t row = (size_t)s * ROWS + b * Nseq + orow_base + r;
            op[row * Dmod + h * DHd + ct * 16 + t] = (__bf16)o[ct][r];
        }
}

// ---------------- merge split-K partials (bf16 in, bf16 out) ----------------
__global__ __launch_bounds__(256) void merge_kernel(
    const __bf16* __restrict__ op, const float* __restrict__ lp,
    __bf16* __restrict__ ctx)
{
    int idx = blockIdx.x * 256 + threadIdx.x;
    int row = idx >> 7, c4 = (idx & 127) * 4;
    int h = c4 >> 6;
    int b = row >> 11, n = row & 2047;
    float l = 0.0f;
#pragma unroll
    for (int s = 0; s < NSPLIT; ++s)
        l += lp[(((size_t)s * Bdim + b) * Hn + h) * Nseq + n];
    float rl = __builtin_amdgcn_rcpf(l);
    float oa[4] = {0.f, 0.f, 0.f, 0.f};
#pragma unroll
    for (int s = 0; s < NSPLIT; ++s) {
        bf16x4 ov = *(const bf16x4*)(op + ((size_t)s * ROWS + row) * Dmod + c4);
#pragma unroll
        for (int j = 0; j < 4; ++j) oa[j] += (float)ov[j];
    }
    bf16x4 r;
#pragma unroll
    for (int j = 0; j < 4; ++j) r[j] = (__bf16)(oa[j] * rl);
    *(bf16x4*)(ctx + (size_t)row * Dmod + c4) = r;
}

// ---------------- launch ----------------
extern "C" void kernel_launch(void* const* d_in, const int* in_sizes, int n_in,
                              void* d_out, int out_size, void* d_ws, size_t ws_size,
                              hipStream_t stream)
{
    (void)in_sizes; (void)n_in; (void)out_size; (void)ws_size;
    const float* x      = (const float*)d_in[0];
    const float* coords = (const float*)d_in[1];
    const float* q_w    = (const float*)d_in[2];
    const float* q_b    = (const float*)d_in[3];
    const float* k_w    = (const float*)d_in[4];
    const float* k_b    = (const float*)d_in[5];
    const float* v_w    = (const float*)d_in[6];
    const float* v_b    = (const float*)d_in[7];
    const float* o_w    = (const float*)d_in[8];
    const float* o_b    = (const float*)d_in[9];
    const float* gamma1 = (const float*)d_in[10];
    const float* ln1_w  = (const float*)d_in[11];
    const float* ln1_b  = (const float*)d_in[12];
    const float* fc1_w  = (const float*)d_in[13];
    const float* fc1_b  = (const float*)d_in[14];
    const float* fc2_w  = (const float*)d_in[15];
    const float* fc2_b  = (const float*)d_in[16];
    const float* gamma2 = (const float*)d_in[17];
    const float* ln2_w  = (const float*)d_in[18];
    const float* ln2_b  = (const float*)d_in[19];

    size_t off = 0;
    auto alloc = [&](size_t bytes) {
        void* p = (char*)d_ws + off;
        off += (bytes + 255) & ~(size_t)255;
        return p;
    };
    __bf16*   wqkv  = (__bf16*)alloc((size_t)1536 * 512 * 2);
    __bf16*   wo    = (__bf16*)alloc((size_t)512 * 512 * 2);
    __bf16*   wfc1p = (__bf16*)alloc((size_t)NPACK * 512 * 2);
    __bf16*   wfc2p = (__bf16*)alloc((size_t)512 * HC * 2);
    __bf16*   xn    = (__bf16*)alloc((size_t)ROWS * Dmod * 2);
    __bf16*   xn2   = (__bf16*)alloc((size_t)ROWS * Dmod * 2);
    __bf16*   qkb   = (__bf16*)alloc((size_t)ROWS * 1024 * 2);
    __bf16*   vtg   = (__bf16*)alloc((size_t)Bdim * Hn * DHd * Nseq * 2);
    __bf16*   ctxb  = (__bf16*)alloc((size_t)ROWS * Dmod * 2);
    float*    x1    = (float*)alloc((size_t)ROWS * Dmod * 4);
    __bf16*   hcomb = (__bf16*)alloc((size_t)ROWS * HC * 2);
    __bf16*   opb   = (__bf16*)alloc((size_t)NSPLIT * ROWS * Dmod * 2);
    float*    lpb   = (float*)alloc((size_t)NSPLIT * Bdim * Hn * Nseq * 4);
    _Float16* distb = (_Float16*)alloc((size_t)Bdim * Nseq * Nseq * 2);

    convert_ln<<<CONV_BLOCKS + ROWS + DIST_BLOCKS, 256, 0, stream>>>(
        q_w, k_w, v_w, o_w, fc1_w, fc2_w, wqkv, wo, wfc1p, wfc2p,
        x, ln1_w, ln1_b, xn, coords, distb);

    qkv_gemm128<<<dim3(ROWS / 128, 12), 256, 0, stream>>>(xn, wqkv, q_b, k_b, v_b, qkb, vtg);

    attn_kernel<<<dim3(Nseq / 64, Hn, Bdim * NSPLIT), 256, 0, stream>>>(
        qkb, vtg, distb, opb, lpb, Nseq / 64 / NSPLIT);
    merge_kernel<<<(ROWS * 128 + 255) / 256, 256, 0, stream>>>(opb, lpb, ctxb);

    gemm_res<<<dim3(ROWS / 64, Dmod / 64), 512, 0, stream>>>(
        ctxb, Dmod, wo, Dmod, o_b, Dmod, x1, Dmod, x, gamma1);

    ln_kernel<<<ROWS, 256, 0, stream>>>(x1, ln2_w, ln2_b, xn2);

    fc1_gemm128<<<dim3(ROWS / 128, NPACK / 128), 256, 0, stream>>>(xn2, wfc1p, fc1_b, hcomb);

    gemm_res<<<dim3(ROWS / 64, Dmod / 64), 512, 0, stream>>>(
        hcomb, HC, wfc2p, HC, fc2_b, HC, (float*)d_out, Dmod, x1, gamma2);
}

// Round 11
// 222.037 us; speedup vs baseline: 1.0524x; 1.0524x over previous
//
#include <hip/hip_runtime.h>
#include <math.h>

#define Bdim  2
#define Nseq  2048
#define Dmod  512
#define Hn    8
#define DHd   64
#define HID   2730
#define HHALF 1365
#define HC    1408      // combined hidden, padded (22*64)
#define NPACK 2816      // packed fc1 output cols (2*HC)
#define ROWS  4096      // Bdim*Nseq
#define NSPLIT 2        // attention split-K

typedef __bf16 bf16x8 __attribute__((ext_vector_type(8)));
typedef __bf16 bf16x4 __attribute__((ext_vector_type(4)));
typedef float  f32x4  __attribute__((ext_vector_type(4)));

__device__ __forceinline__ void glds16(const __bf16* g, __bf16* l) {
    __builtin_amdgcn_global_load_lds(
        (const __attribute__((address_space(1))) void*)g,
        (__attribute__((address_space(3))) void*)l, 16, 0, 0);
}

// ---------------- LN body (shared) ----------------
__device__ __forceinline__ void ln_body(
    int row, int tid, const float* __restrict__ x, const float* __restrict__ w,
    const float* __restrict__ b, __bf16* __restrict__ out)
{
    const float* xr = x + (size_t)row * Dmod;
    float2 v = *(const float2*)(xr + tid * 2);
    float s  = v.x + v.y;
    float sq = v.x * v.x + v.y * v.y;
#pragma unroll
    for (int m = 1; m < 64; m <<= 1) {
        s  += __shfl_xor(s, m, 64);
        sq += __shfl_xor(sq, m, 64);
    }
    __shared__ float ss[4], ssq[4];
    const int wv = tid >> 6;
    if ((tid & 63) == 0) { ss[wv] = s; ssq[wv] = sq; }
    __syncthreads();
    s  = ss[0] + ss[1] + ss[2] + ss[3];
    sq = ssq[0] + ssq[1] + ssq[2] + ssq[3];
    const float mean = s * (1.0f / Dmod);
    const float var  = sq * (1.0f / Dmod) - mean * mean;
    const float rstd = rsqrtf(var + 1e-5f);
    float2 wv2 = *(const float2*)(w + tid * 2);
    float2 bv2 = *(const float2*)(b + tid * 2);
    __bf16* orow = out + (size_t)row * Dmod + tid * 2;
    orow[0] = (__bf16)((v.x - mean) * rstd * wv2.x + bv2.x);
    orow[1] = (__bf16)((v.y - mean) * rstd * wv2.y + bv2.y);
}

// ---------------- fused weight conversion + LN1 ----------------
#define SEG0 (1536*512)
#define SEG1 (512*512)
#define SEG2 (NPACK*512)
#define SEG3 (512*HC)
#define CONV_BLOCKS ((SEG0 + SEG1 + SEG2 + SEG3) / 256)
__global__ __launch_bounds__(256) void convert_ln(
    const float* __restrict__ q_w, const float* __restrict__ k_w,
    const float* __restrict__ v_w, const float* __restrict__ o_w,
    const float* __restrict__ fc1_w, const float* __restrict__ fc2_w,
    __bf16* __restrict__ wqkv, __bf16* __restrict__ wo,
    __bf16* __restrict__ wfc1p, __bf16* __restrict__ wfc2p,
    const float* __restrict__ x, const float* __restrict__ ln1w,
    const float* __restrict__ ln1b, __bf16* __restrict__ xn)
{
    if (blockIdx.x >= CONV_BLOCKS) {
        ln_body(blockIdx.x - CONV_BLOCKS, threadIdx.x, x, ln1w, ln1b, xn);
        return;
    }
    int idx = blockIdx.x * 256 + threadIdx.x;
    if (idx < SEG0) {
        int n = idx >> 9, k = idx & 511;
        float v = (n < 512) ? q_w[n * 512 + k]
                : (n < 1024) ? k_w[(n - 512) * 512 + k]
                : v_w[(n - 1024) * 512 + k];
        wqkv[idx] = (__bf16)v;
        return;
    }
    idx -= SEG0;
    if (idx < SEG1) { wo[idx] = (__bf16)o_w[idx]; return; }
    idx -= SEG1;
    if (idx < SEG2) {
        int n = idx >> 9, k = idx & 511;
        int j = n >> 5, u = n & 31;
        int base = j * 16 + (u & 15);
        float v = 0.0f;
        if (base < HHALF) {
            int hidx = base + ((u & 16) ? HHALF : 0);
            v = fc1_w[(size_t)hidx * 512 + k];
        }
        wfc1p[idx] = (__bf16)v;
        return;
    }
    idx -= SEG2;
    if (idx < SEG3) {
        int n = idx / HC, k = idx - n * HC;
        float v = (k < HHALF) ? fc2_w[(size_t)n * HHALF + k] : 0.0f;
        wfc2p[idx] = (__bf16)v;
    }
}

// ---------------- LN2 ----------------
__global__ __launch_bounds__(256) void ln_kernel(
    const float* __restrict__ x, const float* __restrict__ w,
    const float* __restrict__ b, __bf16* __restrict__ out)
{
    ln_body(blockIdx.x, threadIdx.x, x, w, b, out);
}

// ---------------- 64x64 residual GEMM, 8 waves, K-parallel x2, XOR-swizzled LDS ----------------
__global__ __launch_bounds__(512) void gemm_res(
    const __bf16* __restrict__ A, int lda,
    const __bf16* __restrict__ Bw, int ldb,
    const float* __restrict__ bias, int K,
    float* __restrict__ out_f32, int ld_out,
    const float* __restrict__ res, const float* __restrict__ g)
{
    __shared__ __bf16 smem[2 * 64 * 64];
    __bf16* As = smem;
    __bf16* Bs = smem + 64 * 64;
    const int tid  = threadIdx.x;
    const int wave = tid >> 6, lane = tid & 63;
    const int t    = lane & 15, quad = lane >> 4;
    const int kg   = wave >> 2, wv = wave & 3;
    const int m0   = blockIdx.x * 64;
    const int n0   = blockIdx.y * 64;

    const int srow = tid >> 3;
    const int gch  = ((tid & 7) ^ (srow & 7)) * 8;
    const __bf16* aptr = A  + (size_t)(m0 + srow) * lda + gch;
    const __bf16* bptr = Bw + (size_t)(n0 + srow) * ldb + gch;

    const int arow = wv * 16 + t;
    const int aoff = arow * 64 + (((kg * 4 + quad) ^ (arow & 7)) * 8);
    int boffs[4];
#pragma unroll
    for (int ct = 0; ct < 4; ++ct) {
        int brow = ct * 16 + t;
        boffs[ct] = brow * 64 + (((kg * 4 + quad) ^ (brow & 7)) * 8);
    }

    f32x4 acc[4] = {};
    for (int k0 = 0; k0 < K; k0 += 64) {
        __syncthreads();
        glds16(aptr + k0, As + tid * 8);
        glds16(bptr + k0, Bs + tid * 8);
        __syncthreads();
        bf16x8 a = *(const bf16x8*)(As + aoff);
#pragma unroll
        for (int ct = 0; ct < 4; ++ct) {
            bf16x8 b = *(const bf16x8*)(Bs + boffs[ct]);
            acc[ct] = __builtin_amdgcn_mfma_f32_16x16x32_bf16(a, b, acc[ct], 0, 0, 0);
        }
    }

    __syncthreads();
    if (kg == 1) {
        float* dst = (float*)smem + ((size_t)wv * 64 + lane) * 16;
#pragma unroll
        for (int ct = 0; ct < 4; ++ct) *(f32x4*)(dst + ct * 4) = acc[ct];
    }
    __syncthreads();
    if (kg == 0) {
        const float* src = (const float*)smem + ((size_t)wv * 64 + lane) * 16;
        const int row_base = m0 + wv * 16 + quad * 4;
#pragma unroll
        for (int ct = 0; ct < 4; ++ct) {
            f32x4 other = *(const f32x4*)(src + ct * 4);
            const int col = n0 + ct * 16 + t;
            const float bb = bias[col];
#pragma unroll
            for (int r = 0; r < 4; ++r) {
                const int row = row_base + r;
                out_f32[(size_t)row * ld_out + col] =
                    res[(size_t)row * ld_out + col] +
                    g[col] * (acc[ct][r] + other[r] + bb);
            }
        }
    }
}

// ---------------- 128x128 QKV GEMM (BK=32); V written transposed via LDS ----------------
#define LDT 136
__global__ __launch_bounds__(256) void qkv_gemm128(
    const __bf16* __restrict__ A, const __bf16* __restrict__ W,
    const float* __restrict__ qb_, const float* __restrict__ kb_,
    const float* __restrict__ vb_,
    __bf16* __restrict__ qk, __bf16* __restrict__ vtg)
{
    __shared__ __bf16 smem[64 * LDT];
    __bf16* As = smem;
    __bf16* Bs = smem + 4096;
    const int tid  = threadIdx.x;
    const int wave = tid >> 6, lane = tid & 63;
    const int t    = lane & 15, quad = lane >> 4;
    const int m0   = blockIdx.x * 128, n0 = blockIdx.y * 128;
    const int mr   = (wave & 1) * 64,  nr = (wave >> 1) * 64;
    const int ra0 = tid >> 2,          ca0 = (tid & 3) * 8;
    const int ra1 = (tid + 256) >> 2,  ca1 = (tid & 3) * 8;

    f32x4 acc[4][4] = {};

    for (int k0 = 0; k0 < Dmod; k0 += 32) {
        __syncthreads();
        glds16(A + (size_t)(m0 + ra0) * Dmod + k0 + ca0, As + tid * 8);
        glds16(A + (size_t)(m0 + ra1) * Dmod + k0 + ca1, As + (tid + 256) * 8);
        glds16(W + (size_t)(n0 + ra0) * Dmod + k0 + ca0, Bs + tid * 8);
        glds16(W + (size_t)(n0 + ra1) * Dmod + k0 + ca1, Bs + (tid + 256) * 8);
        __syncthreads();
        bf16x8 af[4], bfr[4];
#pragma unroll
        for (int mi = 0; mi < 4; ++mi)
            af[mi] = *(const bf16x8*)(As + (mr + mi * 16 + t) * 32 + quad * 8);
#pragma unroll
        for (int ni = 0; ni < 4; ++ni)
            bfr[ni] = *(const bf16x8*)(Bs + (nr + ni * 16 + t) * 32 + quad * 8);
#pragma unroll
        for (int mi = 0; mi < 4; ++mi)
#pragma unroll
            for (int ni = 0; ni < 4; ++ni)
                acc[mi][ni] = __builtin_amdgcn_mfma_f32_16x16x32_bf16(af[mi], bfr[ni], acc[mi][ni], 0, 0, 0);
    }

    const int y = blockIdx.y;
    if (y < 8) {
#pragma unroll
        for (int mi = 0; mi < 4; ++mi) {
            const int row_base = m0 + mr + mi * 16 + quad * 4;
#pragma unroll
            for (int ni = 0; ni < 4; ++ni) {
                const int col = n0 + nr + ni * 16 + t;
                const float bb = (col < 512) ? qb_[col] : kb_[col - 512];
#pragma unroll
                for (int r = 0; r < 4; ++r)
                    qk[(size_t)(row_base + r) * 1024 + col] = (__bf16)(acc[mi][ni][r] + bb);
            }
        }
    } else {
        const int tok0 = m0 & 2047;
        const int bI   = m0 >> 11;
#pragma unroll
        for (int half = 0; half < 2; ++half) {
            __syncthreads();
            if ((wave >> 1) == half) {
#pragma unroll
                for (int ni = 0; ni < 4; ++ni) {
                    const int dh = ni * 16 + t;
                    const float bb = vb_[(y - 8) * 128 + half * 64 + dh];
#pragma unroll
                    for (int mi = 0; mi < 4; ++mi) {
                        const int n = mr + mi * 16 + quad * 4;
                        bf16x4 pk;
#pragma unroll
                        for (int r = 0; r < 4; ++r) pk[r] = (__bf16)(acc[mi][ni][r] + bb);
                        *(bf16x4*)(smem + dh * LDT + n) = pk;
                    }
                }
            }
            __syncthreads();
            const int hh = (y - 8) * 2 + half;
            const size_t rowbase = (size_t)(bI * 8 + hh) * 64;
#pragma unroll
            for (int j = 0; j < 4; ++j) {
                int chunk = tid + j * 256;
                int dr = chunk >> 4, cc = (chunk & 15) * 8;
                bf16x8 vv = *(const bf16x8*)(smem + dr * LDT + cc);
                *(bf16x8*)(vtg + (rowbase + dr) * Nseq + tok0 + cc) = vv;
            }
        }
    }
}

// ---------------- 128x128 fc1 GEMM (BK=32) with fused SwiGLU epilogue ----------------
__global__ __launch_bounds__(256) void fc1_gemm128(
    const __bf16* __restrict__ A, const __bf16* __restrict__ W,
    const float* __restrict__ fc1_b_, __bf16* __restrict__ out)
{
    __shared__ __bf16 As[128 * 32];
    __shared__ __bf16 Bs[128 * 32];
    const int tid  = threadIdx.x;
    const int wave = tid >> 6, lane = tid & 63;
    const int t    = lane & 15, quad = lane >> 4;
    const int m0   = blockIdx.x * 128, n0 = blockIdx.y * 128;
    const int mr   = (wave & 1) * 64,  nr = (wave >> 1) * 64;
    const int ra0 = tid >> 2,          ca0 = (tid & 3) * 8;
    const int ra1 = (tid + 256) >> 2,  ca1 = (tid & 3) * 8;

    f32x4 acc[4][4] = {};

    for (int k0 = 0; k0 < Dmod; k0 += 32) {
        __syncthreads();
        glds16(A + (size_t)(m0 + ra0) * Dmod + k0 + ca0, As + tid * 8);
        glds16(A + (size_t)(m0 + ra1) * Dmod + k0 + ca1, As + (tid + 256) * 8);
        glds16(W + (size_t)(n0 + ra0) * Dmod + k0 + ca0, Bs + tid * 8);
        glds16(W + (size_t)(n0 + ra1) * Dmod + k0 + ca1, Bs + (tid + 256) * 8);
        __syncthreads();
        bf16x8 af[4], bfr[4];
#pragma unroll
        for (int mi = 0; mi < 4; ++mi)
            af[mi] = *(const bf16x8*)(As + (mr + mi * 16 + t) * 32 + quad * 8);
#pragma unroll
        for (int ni = 0; ni < 4; ++ni)
            bfr[ni] = *(const bf16x8*)(Bs + (nr + ni * 16 + t) * 32 + quad * 8);
#pragma unroll
        for (int mi = 0; mi < 4; ++mi)
#pragma unroll
            for (int ni = 0; ni < 4; ++ni)
                acc[mi][ni] = __builtin_amdgcn_mfma_f32_16x16x32_bf16(af[mi], bfr[ni], acc[mi][ni], 0, 0, 0);
    }

#pragma unroll
    for (int mi = 0; mi < 4; ++mi) {
        const int row_base = m0 + mr + mi * 16 + quad * 4;
#pragma unroll
        for (int gI = 0; gI < 2; ++gI) {
            const int base = n0 + nr + gI * 32;
            const int hb = (base >> 5) * 16 + t;
            const bool valid = hb < HHALF;
            const float b1 = valid ? fc1_b_[hb] : 0.0f;
            const float b2 = valid ? fc1_b_[HHALF + hb] : 0.0f;
#pragma unroll
            for (int r = 0; r < 4; ++r) {
                float a = acc[mi][2 * gI][r] + b1;
                float c = acc[mi][2 * gI + 1][r] + b2;
                float sw = a / (1.0f + __expf(-a)) * c;
                out[(size_t)(row_base + r) * HC + hb] = (__bf16)sw;
            }
        }
    }
}

// ---------------- Flash attention, split-K, no-max softmax ----------------
// Single-barrier double-buffered K/V staging: compute buf[p] while staging buf[p^1].
__global__ __launch_bounds__(256) void attn_kernel(
    const __bf16* __restrict__ qk, const __bf16* __restrict__ vt,
    const float* __restrict__ coords,
    __bf16* __restrict__ op, float* __restrict__ lp, int ktper)
{
    constexpr int LD = 72;
    __shared__ __bf16 Ks[2][64][LD];
    __shared__ __bf16 Vt[2][64][LD];
    __shared__ __bf16 Ps[64][LD];
    __shared__ float2 kco[2][64];

    const int qt = blockIdx.x, h = blockIdx.y;
    const int s = blockIdx.z >> 1, b = blockIdx.z & 1;
    const int bh = b * Hn + h;
    const int tid = threadIdx.x;
    const int wave = tid >> 6, lane = tid & 63;
    const int t = lane & 15, quad = lane >> 4;
    const float c1 = 0.125f * 1.44269504f;
    const float d1 = exp2f(-(float)(h + 1)) * 1.44269504f;

    const int qrow = qt * 64 + wave * 16 + t;
    const size_t qbase = (size_t)(b * Nseq + qrow) * 1024 + h * DHd;
    bf16x8 bq0 = *(const bf16x8*)(qk + qbase + quad * 8);
    bf16x8 bq1 = *(const bf16x8*)(qk + qbase + 32 + quad * 8);
    float2 qc = *(const float2*)(coords + (size_t)(b * Nseq + qrow) * 2);
    const float qx = qc.x, qy = qc.y;

    const int sr = tid >> 3, scc = (tid & 7) * 8;
    const __bf16* kbase = qk + (size_t)(b * Nseq) * 1024 + 512 + h * DHd;
    const __bf16* vbase = vt + (size_t)(bh * 64) * Nseq;

    bf16x8 kreg0, kreg1, vreg0, vreg1;
    float2 kcreg = {0.f, 0.f};
    int kn = s * ktper * 64;
    // tile 0 -> regs -> buf 0
    kreg0 = *(const bf16x8*)(kbase + (size_t)(kn + sr) * 1024 + scc);
    kreg1 = *(const bf16x8*)(kbase + (size_t)(kn + sr + 32) * 1024 + scc);
    vreg0 = *(const bf16x8*)(vbase + (size_t)sr * Nseq + kn + scc);
    vreg1 = *(const bf16x8*)(vbase + (size_t)(sr + 32) * Nseq + kn + scc);
    if (tid < 64) kcreg = *(const float2*)(coords + (size_t)(b * Nseq + kn + tid) * 2);
    *(bf16x8*)(&Ks[0][sr][scc])      = kreg0;
    *(bf16x8*)(&Ks[0][sr + 32][scc]) = kreg1;
    *(bf16x8*)(&Vt[0][sr][scc])      = vreg0;
    *(bf16x8*)(&Vt[0][sr + 32][scc]) = vreg1;
    if (tid < 64) kco[0][tid] = kcreg;
    __syncthreads();

    f32x4 o[4] = {};
    float lrun = 0.0f;

    for (int it = 0; it < ktper; ++it) {
        const int p = it & 1;
        const bool havenext = (it + 1 < ktper);
        if (havenext) {                  // prefetch next tile (overlaps compute)
            const int k2 = kn + 64;
            kreg0 = *(const bf16x8*)(kbase + (size_t)(k2 + sr) * 1024 + scc);
            kreg1 = *(const bf16x8*)(kbase + (size_t)(k2 + sr + 32) * 1024 + scc);
            vreg0 = *(const bf16x8*)(vbase + (size_t)sr * Nseq + k2 + scc);
            vreg1 = *(const bf16x8*)(vbase + (size_t)(sr + 32) * Nseq + k2 + scc);
            if (tid < 64) kcreg = *(const float2*)(coords + (size_t)(b * Nseq + k2 + tid) * 2);
        }

        // S^T = K·Q^T on buf p
        f32x4 sA[4];
#pragma unroll
        for (int am = 0; am < 4; ++am) {
            bf16x8 a0 = *(const bf16x8*)(&Ks[p][am * 16 + t][quad * 8]);
            bf16x8 a1 = *(const bf16x8*)(&Ks[p][am * 16 + t][32 + quad * 8]);
            f32x4 z = {};
            z = __builtin_amdgcn_mfma_f32_16x16x32_bf16(a0, bq0, z, 0, 0, 0);
            sA[am] = __builtin_amdgcn_mfma_f32_16x16x32_bf16(a1, bq1, z, 0, 0, 0);
        }

        float p4[4][4];
#pragma unroll
        for (int am = 0; am < 4; ++am)
#pragma unroll
            for (int r = 0; r < 4; ++r) {
                float2 kc = kco[p][am * 16 + quad * 4 + r];
                float dx = qx - kc.x, dy = qy - kc.y;
                float dist = __builtin_amdgcn_sqrtf(dx * dx + dy * dy);
                float e = __builtin_amdgcn_exp2f(sA[am][r] * c1 - d1 * dist);
                p4[am][r] = e;
                lrun += e;
            }

#pragma unroll
        for (int am = 0; am < 4; ++am) {
            bf16x4 pk;
#pragma unroll
            for (int r = 0; r < 4; ++r) pk[r] = (__bf16)p4[am][r];
            *(bf16x4*)(&Ps[wave * 16 + t][am * 16 + quad * 4]) = pk;
        }

        bf16x8 ap0 = *(const bf16x8*)(&Ps[wave * 16 + t][quad * 8]);
        bf16x8 ap1 = *(const bf16x8*)(&Ps[wave * 16 + t][32 + quad * 8]);
#pragma unroll
        for (int ct = 0; ct < 4; ++ct) {
            bf16x8 bv0 = *(const bf16x8*)(&Vt[p][ct * 16 + t][quad * 8]);
            bf16x8 bv1 = *(const bf16x8*)(&Vt[p][ct * 16 + t][32 + quad * 8]);
            o[ct] = __builtin_amdgcn_mfma_f32_16x16x32_bf16(ap0, bv0, o[ct], 0, 0, 0);
            o[ct] = __builtin_amdgcn_mfma_f32_16x16x32_bf16(ap1, bv1, o[ct], 0, 0, 0);
        }

        // stage next tile into buf p^1; ONE barrier per iteration
        if (havenext) {
            *(bf16x8*)(&Ks[p ^ 1][sr][scc])      = kreg0;
            *(bf16x8*)(&Ks[p ^ 1][sr + 32][scc]) = kreg1;
            *(bf16x8*)(&Vt[p ^ 1][sr][scc])      = vreg0;
            *(bf16x8*)(&Vt[p ^ 1][sr + 32][scc]) = vreg1;
            if (tid < 64) kco[p ^ 1][tid] = kcreg;
        }
        __syncthreads();
        kn += 64;
    }

    lrun += __shfl_xor(lrun, 16, 64);
    lrun += __shfl_xor(lrun, 32, 64);
    if (quad == 0)
        lp[(((size_t)s * Bdim + b) * Hn + h) * Nseq + qt * 64 + wave * 16 + t] = lrun;

    const int orow_base = qt * 64 + wave * 16 + quad * 4;
#pragma unroll
    for (int ct = 0; ct < 4; ++ct)
#pragma unroll
        for (int r = 0; r < 4; ++r) {
            size_t row = (size_t)s * ROWS + b * Nseq + orow_base + r;
            op[row * Dmod + h * DHd + ct * 16 + t] = (__bf16)o[ct][r];
        }
}

// ---------------- merge split-K partials (bf16 in, bf16 out) ----------------
__global__ __launch_bounds__(256) void merge_kernel(
    const __bf16* __restrict__ op, const float* __restrict__ lp,
    __bf16* __restrict__ ctx)
{
    int idx = blockIdx.x * 256 + threadIdx.x;
    int row = idx >> 7, c4 = (idx & 127) * 4;
    int h = c4 >> 6;
    int b = row >> 11, n = row & 2047;
    float l = 0.0f;
#pragma unroll
    for (int s = 0; s < NSPLIT; ++s)
        l += lp[(((size_t)s * Bdim + b) * Hn + h) * Nseq + n];
    float rl = __builtin_amdgcn_rcpf(l);
    float oa[4] = {0.f, 0.f, 0.f, 0.f};
#pragma unroll
    for (int s = 0; s < NSPLIT; ++s) {
        bf16x4 ov = *(const bf16x4*)(op + ((size_t)s * ROWS + row) * Dmod + c4);
#pragma unroll
        for (int j = 0; j < 4; ++j) oa[j] += (float)ov[j];
    }
    bf16x4 r;
#pragma unroll
    for (int j = 0; j < 4; ++j) r[j] = (__bf16)(oa[j] * rl);
    *(bf16x4*)(ctx + (size_t)row * Dmod + c4) = r;
}

// ---------------- launch ----------------
extern "C" void kernel_launch(void* const* d_in, const int* in_sizes, int n_in,
                              void* d_out, int out_size, void* d_ws, size_t ws_size,
                              hipStream_t stream)
{
    (void)in_sizes; (void)n_in; (void)out_size; (void)ws_size;
    const float* x      = (const float*)d_in[0];
    const float* coords = (const float*)d_in[1];
    const float* q_w    = (const float*)d_in[2];
    const float* q_b    = (const float*)d_in[3];
    const float* k_w    = (const float*)d_in[4];
    const float* k_b    = (const float*)d_in[5];
    const float* v_w    = (const float*)d_in[6];
    const float* v_b    = (const float*)d_in[7];
    const float* o_w    = (const float*)d_in[8];
    const float* o_b    = (const float*)d_in[9];
    const float* gamma1 = (const float*)d_in[10];
    const float* ln1_w  = (const float*)d_in[11];
    const float* ln1_b  = (const float*)d_in[12];
    const float* fc1_w  = (const float*)d_in[13];
    const float* fc1_b  = (const float*)d_in[14];
    const float* fc2_w  = (const float*)d_in[15];
    const float* fc2_b  = (const float*)d_in[16];
    const float* gamma2 = (const float*)d_in[17];
    const float* ln2_w  = (const float*)d_in[18];
    const float* ln2_b  = (const float*)d_in[19];

    size_t off = 0;
    auto alloc = [&](size_t bytes) {
        void* p = (char*)d_ws + off;
        off += (bytes + 255) & ~(size_t)255;
        return p;
    };
    __bf16* wqkv  = (__bf16*)alloc((size_t)1536 * 512 * 2);
    __bf16* wo    = (__bf16*)alloc((size_t)512 * 512 * 2);
    __bf16* wfc1p = (__bf16*)alloc((size_t)NPACK * 512 * 2);
    __bf16* wfc2p = (__bf16*)alloc((size_t)512 * HC * 2);
    __bf16* xn    = (__bf16*)alloc((size_t)ROWS * Dmod * 2);
    __bf16* xn2   = (__bf16*)alloc((size_t)ROWS * Dmod * 2);
    __bf16* qkb   = (__bf16*)alloc((size_t)ROWS * 1024 * 2);
    __bf16* vtg   = (__bf16*)alloc((size_t)Bdim * Hn * DHd * Nseq * 2);
    __bf16* ctxb  = (__bf16*)alloc((size_t)ROWS * Dmod * 2);
    float*  x1    = (float*)alloc((size_t)ROWS * Dmod * 4);
    __bf16* hcomb = (__bf16*)alloc((size_t)ROWS * HC * 2);
    __bf16* opb   = (__bf16*)alloc((size_t)NSPLIT * ROWS * Dmod * 2);
    float*  lpb   = (float*)alloc((size_t)NSPLIT * Bdim * Hn * Nseq * 4);

    convert_ln<<<CONV_BLOCKS + ROWS, 256, 0, stream>>>(
        q_w, k_w, v_w, o_w, fc1_w, fc2_w, wqkv, wo, wfc1p, wfc2p,
        x, ln1_w, ln1_b, xn);

    qkv_gemm128<<<dim3(ROWS / 128, 12), 256, 0, stream>>>(xn, wqkv, q_b, k_b, v_b, qkb, vtg);

    attn_kernel<<<dim3(Nseq / 64, Hn, Bdim * NSPLIT), 256, 0, stream>>>(
        qkb, vtg, coords, opb, lpb, Nseq / 64 / NSPLIT);
    merge_kernel<<<(ROWS * 128 + 255) / 256, 256, 0, stream>>>(opb, lpb, ctxb);

    gemm_res<<<dim3(ROWS / 64, Dmod / 64), 512, 0, stream>>>(
        ctxb, Dmod, wo, Dmod, o_b, Dmod, x1, Dmod, x, gamma1);

    ln_kernel<<<ROWS, 256, 0, stream>>>(x1, ln2_w, ln2_b, xn2);

    fc1_gemm128<<<dim3(ROWS / 128, NPACK / 128), 256, 0, stream>>>(xn2, wfc1p, fc1_b, hcomb);

    gemm_res<<<dim3(ROWS / 64, Dmod / 64), 512, 0, stream>>>(
        hcomb, HC, wfc2p, HC, fc2_b, HC, (float*)d_out, Dmod, x1, gamma2);
}

// Round 12
// 213.495 us; speedup vs baseline: 1.0945x; 1.0400x over previous
//
#include <hip/hip_runtime.h>
#include <math.h>

#define Bdim  2
#define Nseq  2048
#define Dmod  512
#define Hn    8
#define DHd   64
#define HID   2730
#define HHALF 1365
#define HC    1408      // combined hidden, padded (22*64)
#define NPACK 2816      // packed fc1 output cols (2*HC)
#define ROWS  4096      // Bdim*Nseq
#define NSPLIT 2        // attention split-K (r7-frozen config)

typedef __bf16 bf16x8 __attribute__((ext_vector_type(8)));
typedef __bf16 bf16x4 __attribute__((ext_vector_type(4)));
typedef __bf16 bf16x2 __attribute__((ext_vector_type(2)));
typedef float  f32x4  __attribute__((ext_vector_type(4)));

__device__ __forceinline__ void glds16(const __bf16* g, __bf16* l) {
    __builtin_amdgcn_global_load_lds(
        (const __attribute__((address_space(1))) void*)g,
        (__attribute__((address_space(3))) void*)l, 16, 0, 0);
}

// ---------------- LN bodies ----------------
__device__ __forceinline__ void ln_core(
    int tid, float vx, float vy, const float* __restrict__ w,
    const float* __restrict__ b, __bf16* __restrict__ orow)
{
    float s  = vx + vy;
    float sq = vx * vx + vy * vy;
#pragma unroll
    for (int m = 1; m < 64; m <<= 1) {
        s  += __shfl_xor(s, m, 64);
        sq += __shfl_xor(sq, m, 64);
    }
    __shared__ float ss[4], ssq[4];
    const int wv = tid >> 6;
    if ((tid & 63) == 0) { ss[wv] = s; ssq[wv] = sq; }
    __syncthreads();
    s  = ss[0] + ss[1] + ss[2] + ss[3];
    sq = ssq[0] + ssq[1] + ssq[2] + ssq[3];
    const float mean = s * (1.0f / Dmod);
    const float var  = sq * (1.0f / Dmod) - mean * mean;
    const float rstd = rsqrtf(var + 1e-5f);
    float2 wv2 = *(const float2*)(w + tid * 2);
    float2 bv2 = *(const float2*)(b + tid * 2);
    orow[0] = (__bf16)((vx - mean) * rstd * wv2.x + bv2.x);
    orow[1] = (__bf16)((vy - mean) * rstd * wv2.y + bv2.y);
}

// ---------------- fused weight conversion + LN1 ----------------
#define SEG0 (1536*512)
#define SEG1 (512*512)
#define SEG2 (NPACK*512)
#define SEG3 (512*HC)
#define CONV_BLOCKS ((SEG0 + SEG1 + SEG2 + SEG3) / 256)
__global__ __launch_bounds__(256) void convert_ln(
    const float* __restrict__ q_w, const float* __restrict__ k_w,
    const float* __restrict__ v_w, const float* __restrict__ o_w,
    const float* __restrict__ fc1_w, const float* __restrict__ fc2_w,
    __bf16* __restrict__ wqkv, __bf16* __restrict__ wo,
    __bf16* __restrict__ wfc1p, __bf16* __restrict__ wfc2p,
    const float* __restrict__ x, const float* __restrict__ ln1w,
    const float* __restrict__ ln1b, __bf16* __restrict__ xn)
{
    if (blockIdx.x >= CONV_BLOCKS) {
        const int row = blockIdx.x - CONV_BLOCKS, tid = threadIdx.x;
        float2 v = *(const float2*)(x + (size_t)row * Dmod + tid * 2);
        ln_core(tid, v.x, v.y, ln1w, ln1b, xn + (size_t)row * Dmod + tid * 2);
        return;
    }
    int idx = blockIdx.x * 256 + threadIdx.x;
    if (idx < SEG0) {
        int n = idx >> 9, k = idx & 511;
        float v = (n < 512) ? q_w[n * 512 + k]
                : (n < 1024) ? k_w[(n - 512) * 512 + k]
                : v_w[(n - 1024) * 512 + k];
        wqkv[idx] = (__bf16)v;
        return;
    }
    idx -= SEG0;
    if (idx < SEG1) { wo[idx] = (__bf16)o_w[idx]; return; }
    idx -= SEG1;
    if (idx < SEG2) {
        int n = idx >> 9, k = idx & 511;
        int j = n >> 5, u = n & 31;
        int base = j * 16 + (u & 15);
        float v = 0.0f;
        if (base < HHALF) {
            int hidx = base + ((u & 16) ? HHALF : 0);
            v = fc1_w[(size_t)hidx * 512 + k];
        }
        wfc1p[idx] = (__bf16)v;
        return;
    }
    idx -= SEG2;
    if (idx < SEG3) {
        int n = idx / HC, k = idx - n * HC;
        float v = (k < HHALF) ? fc2_w[(size_t)n * HHALF + k] : 0.0f;
        wfc2p[idx] = (__bf16)v;
    }
}

// ---------------- LN2 (bf16 input x1) ----------------
__global__ __launch_bounds__(256) void ln_kernel_bf16(
    const __bf16* __restrict__ x, const float* __restrict__ w,
    const float* __restrict__ b, __bf16* __restrict__ out)
{
    const int row = blockIdx.x, tid = threadIdx.x;
    bf16x2 v2 = *(const bf16x2*)(x + (size_t)row * Dmod + tid * 2);
    ln_core(tid, (float)v2[0], (float)v2[1], w, b, out + (size_t)row * Dmod + tid * 2);
}

// ---------------- 64x64 residual GEMM, 8 waves, K-parallel x2, XOR-swizzled LDS ----------------
// MODE 0 (o-proj): A = merged attention partials (op0+op1)*rcp(l0+l1); res fp32; out bf16.
// MODE 1 (fc2):    A = direct bf16 via glds16;                        res bf16; out fp32.
template<int MODE>
__global__ __launch_bounds__(512) void gemm_res(
    const __bf16* __restrict__ A, int lda,
    const __bf16* __restrict__ opA, const float* __restrict__ lpA,
    const __bf16* __restrict__ Bw, int ldb,
    const float* __restrict__ bias, int K,
    void* __restrict__ outp, const void* __restrict__ resp,
    const float* __restrict__ g)
{
    __shared__ __bf16 smem[2 * 64 * 64];
    __bf16* As = smem;
    __bf16* Bs = smem + 64 * 64;
    const int tid  = threadIdx.x;
    const int wave = tid >> 6, lane = tid & 63;
    const int t    = lane & 15, quad = lane >> 4;
    const int kg   = wave >> 2, wv = wave & 3;
    const int m0   = blockIdx.x * 64;
    const int n0   = blockIdx.y * 64;

    const int srow = tid >> 3;
    const int gch  = ((tid & 7) ^ (srow & 7)) * 8;
    const int grow = m0 + srow;
    const int bI   = grow >> 11, nn = grow & 2047;
    const __bf16* aptr = A  + (size_t)grow * lda + gch;
    const __bf16* bptr = Bw + (size_t)(n0 + srow) * ldb + gch;

    const int arow = wv * 16 + t;
    const int aoff = arow * 64 + (((kg * 4 + quad) ^ (arow & 7)) * 8);
    int boffs[4];
#pragma unroll
    for (int ct = 0; ct < 4; ++ct) {
        int brow = ct * 16 + t;
        boffs[ct] = brow * 64 + (((kg * 4 + quad) ^ (brow & 7)) * 8);
    }

    f32x4 acc[4] = {};
    for (int k0 = 0; k0 < K; k0 += 64) {
        __syncthreads();
        if (MODE == 0) {
            // merged A staging: h = (k0+gch)/64, rl = rcp(l0+l1)
            const int kk = k0 + gch;
            const int h = kk >> 6;
            float l = lpA[((size_t)(bI * Hn) + h) * Nseq + nn]
                    + lpA[((size_t)((Bdim + bI) * Hn) + h) * Nseq + nn];
            float rl = __builtin_amdgcn_rcpf(l);
            bf16x8 a0 = *(const bf16x8*)(opA + (size_t)grow * Dmod + kk);
            bf16x8 a1 = *(const bf16x8*)(opA + ((size_t)ROWS + grow) * Dmod + kk);
            bf16x8 mg;
#pragma unroll
            for (int j = 0; j < 8; ++j)
                mg[j] = (__bf16)(((float)a0[j] + (float)a1[j]) * rl);
            *(bf16x8*)(As + tid * 8) = mg;
        } else {
            glds16(aptr + k0, As + tid * 8);
        }
        glds16(bptr + k0, Bs + tid * 8);
        __syncthreads();
        bf16x8 a = *(const bf16x8*)(As + aoff);
#pragma unroll
        for (int ct = 0; ct < 4; ++ct) {
            bf16x8 b = *(const bf16x8*)(Bs + boffs[ct]);
            acc[ct] = __builtin_amdgcn_mfma_f32_16x16x32_bf16(a, b, acc[ct], 0, 0, 0);
        }
    }

    __syncthreads();
    if (kg == 1) {
        float* dst = (float*)smem + ((size_t)wv * 64 + lane) * 16;
#pragma unroll
        for (int ct = 0; ct < 4; ++ct) *(f32x4*)(dst + ct * 4) = acc[ct];
    }
    __syncthreads();
    if (kg == 0) {
        const float* src = (const float*)smem + ((size_t)wv * 64 + lane) * 16;
        const int row_base = m0 + wv * 16 + quad * 4;
#pragma unroll
        for (int ct = 0; ct < 4; ++ct) {
            f32x4 other = *(const f32x4*)(src + ct * 4);
            const int col = n0 + ct * 16 + t;
            const float bb = bias[col];
#pragma unroll
            for (int r = 0; r < 4; ++r) {
                const int row = row_base + r;
                const float v = (acc[ct][r] + other[r] + bb) * g[col];
                if (MODE == 0) {
                    float rv = ((const float*)resp)[(size_t)row * Dmod + col];
                    ((__bf16*)outp)[(size_t)row * Dmod + col] = (__bf16)(rv + v);
                } else {
                    float rv = (float)((const __bf16*)resp)[(size_t)row * Dmod + col];
                    ((float*)outp)[(size_t)row * Dmod + col] = rv + v;
                }
            }
        }
    }
}

// ---------------- 128x128 QKV GEMM (BK=32); V written transposed via LDS ----------------
#define LDT 136
__global__ __launch_bounds__(256) void qkv_gemm128(
    const __bf16* __restrict__ A, const __bf16* __restrict__ W,
    const float* __restrict__ qb_, const float* __restrict__ kb_,
    const float* __restrict__ vb_,
    __bf16* __restrict__ qk, __bf16* __restrict__ vtg)
{
    __shared__ __bf16 smem[64 * LDT];
    __bf16* As = smem;
    __bf16* Bs = smem + 4096;
    const int tid  = threadIdx.x;
    const int wave = tid >> 6, lane = tid & 63;
    const int t    = lane & 15, quad = lane >> 4;
    const int m0   = blockIdx.x * 128, n0 = blockIdx.y * 128;
    const int mr   = (wave & 1) * 64,  nr = (wave >> 1) * 64;
    const int ra0 = tid >> 2,          ca0 = (tid & 3) * 8;
    const int ra1 = (tid + 256) >> 2,  ca1 = (tid & 3) * 8;

    f32x4 acc[4][4] = {};

    for (int k0 = 0; k0 < Dmod; k0 += 32) {
        __syncthreads();
        glds16(A + (size_t)(m0 + ra0) * Dmod + k0 + ca0, As + tid * 8);
        glds16(A + (size_t)(m0 + ra1) * Dmod + k0 + ca1, As + (tid + 256) * 8);
        glds16(W + (size_t)(n0 + ra0) * Dmod + k0 + ca0, Bs + tid * 8);
        glds16(W + (size_t)(n0 + ra1) * Dmod + k0 + ca1, Bs + (tid + 256) * 8);
        __syncthreads();
        bf16x8 af[4], bfr[4];
#pragma unroll
        for (int mi = 0; mi < 4; ++mi)
            af[mi] = *(const bf16x8*)(As + (mr + mi * 16 + t) * 32 + quad * 8);
#pragma unroll
        for (int ni = 0; ni < 4; ++ni)
            bfr[ni] = *(const bf16x8*)(Bs + (nr + ni * 16 + t) * 32 + quad * 8);
#pragma unroll
        for (int mi = 0; mi < 4; ++mi)
#pragma unroll
            for (int ni = 0; ni < 4; ++ni)
                acc[mi][ni] = __builtin_amdgcn_mfma_f32_16x16x32_bf16(af[mi], bfr[ni], acc[mi][ni], 0, 0, 0);
    }

    const int y = blockIdx.y;
    if (y < 8) {
#pragma unroll
        for (int mi = 0; mi < 4; ++mi) {
            const int row_base = m0 + mr + mi * 16 + quad * 4;
#pragma unroll
            for (int ni = 0; ni < 4; ++ni) {
                const int col = n0 + nr + ni * 16 + t;
                const float bb = (col < 512) ? qb_[col] : kb_[col - 512];
#pragma unroll
                for (int r = 0; r < 4; ++r)
                    qk[(size_t)(row_base + r) * 1024 + col] = (__bf16)(acc[mi][ni][r] + bb);
            }
        }
    } else {
        const int tok0 = m0 & 2047;
        const int bI   = m0 >> 11;
#pragma unroll
        for (int half = 0; half < 2; ++half) {
            __syncthreads();
            if ((wave >> 1) == half) {
#pragma unroll
                for (int ni = 0; ni < 4; ++ni) {
                    const int dh = ni * 16 + t;
                    const float bb = vb_[(y - 8) * 128 + half * 64 + dh];
#pragma unroll
                    for (int mi = 0; mi < 4; ++mi) {
                        const int n = mr + mi * 16 + quad * 4;
                        bf16x4 pk;
#pragma unroll
                        for (int r = 0; r < 4; ++r) pk[r] = (__bf16)(acc[mi][ni][r] + bb);
                        *(bf16x4*)(smem + dh * LDT + n) = pk;
                    }
                }
            }
            __syncthreads();
            const int hh = (y - 8) * 2 + half;
            const size_t rowbase = (size_t)(bI * 8 + hh) * 64;
#pragma unroll
            for (int j = 0; j < 4; ++j) {
                int chunk = tid + j * 256;
                int dr = chunk >> 4, cc = (chunk & 15) * 8;
                bf16x8 vv = *(const bf16x8*)(smem + dr * LDT + cc);
                *(bf16x8*)(vtg + (rowbase + dr) * Nseq + tok0 + cc) = vv;
            }
        }
    }
}

// ---------------- 128x128 fc1 GEMM (BK=32) with fused SwiGLU epilogue ----------------
__global__ __launch_bounds__(256) void fc1_gemm128(
    const __bf16* __restrict__ A, const __bf16* __restrict__ W,
    const float* __restrict__ fc1_b_, __bf16* __restrict__ out)
{
    __shared__ __bf16 As[128 * 32];
    __shared__ __bf16 Bs[128 * 32];
    const int tid  = threadIdx.x;
    const int wave = tid >> 6, lane = tid & 63;
    const int t    = lane & 15, quad = lane >> 4;
    const int m0   = blockIdx.x * 128, n0 = blockIdx.y * 128;
    const int mr   = (wave & 1) * 64,  nr = (wave >> 1) * 64;
    const int ra0 = tid >> 2,          ca0 = (tid & 3) * 8;
    const int ra1 = (tid + 256) >> 2,  ca1 = (tid & 3) * 8;

    f32x4 acc[4][4] = {};

    for (int k0 = 0; k0 < Dmod; k0 += 32) {
        __syncthreads();
        glds16(A + (size_t)(m0 + ra0) * Dmod + k0 + ca0, As + tid * 8);
        glds16(A + (size_t)(m0 + ra1) * Dmod + k0 + ca1, As + (tid + 256) * 8);
        glds16(W + (size_t)(n0 + ra0) * Dmod + k0 + ca0, Bs + tid * 8);
        glds16(W + (size_t)(n0 + ra1) * Dmod + k0 + ca1, Bs + (tid + 256) * 8);
        __syncthreads();
        bf16x8 af[4], bfr[4];
#pragma unroll
        for (int mi = 0; mi < 4; ++mi)
            af[mi] = *(const bf16x8*)(As + (mr + mi * 16 + t) * 32 + quad * 8);
#pragma unroll
        for (int ni = 0; ni < 4; ++ni)
            bfr[ni] = *(const bf16x8*)(Bs + (nr + ni * 16 + t) * 32 + quad * 8);
#pragma unroll
        for (int mi = 0; mi < 4; ++mi)
#pragma unroll
            for (int ni = 0; ni < 4; ++ni)
                acc[mi][ni] = __builtin_amdgcn_mfma_f32_16x16x32_bf16(af[mi], bfr[ni], acc[mi][ni], 0, 0, 0);
    }

#pragma unroll
    for (int mi = 0; mi < 4; ++mi) {
        const int row_base = m0 + mr + mi * 16 + quad * 4;
#pragma unroll
        for (int gI = 0; gI < 2; ++gI) {
            const int base = n0 + nr + gI * 32;
            const int hb = (base >> 5) * 16 + t;
            const bool valid = hb < HHALF;
            const float b1 = valid ? fc1_b_[hb] : 0.0f;
            const float b2 = valid ? fc1_b_[HHALF + hb] : 0.0f;
#pragma unroll
            for (int r = 0; r < 4; ++r) {
                float a = acc[mi][2 * gI][r] + b1;
                float c = acc[mi][2 * gI + 1][r] + b2;
                float sw = a / (1.0f + __expf(-a)) * c;
                out[(size_t)(row_base + r) * HC + hb] = (__bf16)sw;
            }
        }
    }
}

// ---------------- Flash attention (r7-frozen): split-K=2, no-max softmax ----------------
__global__ __launch_bounds__(256) void attn_kernel(
    const __bf16* __restrict__ qk, const __bf16* __restrict__ vt,
    const float* __restrict__ coords,
    __bf16* __restrict__ op, float* __restrict__ lp, int ktper)
{
    constexpr int LD = 72;
    __shared__ __bf16 Ks[64][LD];
    __shared__ __bf16 Vt[64][LD];
    __shared__ __bf16 Ps[64][LD];
    __shared__ float2 kco[64];

    const int qt = blockIdx.x, h = blockIdx.y;
    const int s = blockIdx.z >> 1, b = blockIdx.z & 1;
    const int bh = b * Hn + h;
    const int tid = threadIdx.x;
    const int wave = tid >> 6, lane = tid & 63;
    const int t = lane & 15, quad = lane >> 4;
    const float c1 = 0.125f * 1.44269504f;
    const float d1 = exp2f(-(float)(h + 1)) * 1.44269504f;

    const int qrow = qt * 64 + wave * 16 + t;
    const size_t qbase = (size_t)(b * Nseq + qrow) * 1024 + h * DHd;
    bf16x8 bq0 = *(const bf16x8*)(qk + qbase + quad * 8);
    bf16x8 bq1 = *(const bf16x8*)(qk + qbase + 32 + quad * 8);
    float2 qc = *(const float2*)(coords + (size_t)(b * Nseq + qrow) * 2);
    const float qx = qc.x, qy = qc.y;

    const int sr = tid >> 3, scc = (tid & 7) * 8;
    const __bf16* kbase = qk + (size_t)(b * Nseq) * 1024 + 512 + h * DHd;
    const __bf16* vbase = vt + (size_t)(bh * 64) * Nseq;

    bf16x8 kreg0, kreg1, vreg0, vreg1;
    float2 kcreg = {0.f, 0.f};
    int kn = s * ktper * 64;
    kreg0 = *(const bf16x8*)(kbase + (size_t)(kn + sr) * 1024 + scc);
    kreg1 = *(const bf16x8*)(kbase + (size_t)(kn + sr + 32) * 1024 + scc);
    vreg0 = *(const bf16x8*)(vbase + (size_t)sr * Nseq + kn + scc);
    vreg1 = *(const bf16x8*)(vbase + (size_t)(sr + 32) * Nseq + kn + scc);
    if (tid < 64) kcreg = *(const float2*)(coords + (size_t)(b * Nseq + kn + tid) * 2);

    f32x4 o[4] = {};
    float lrun = 0.0f;

    for (int it = 0; it < ktper; ++it) {
        __syncthreads();
        *(bf16x8*)(&Ks[sr][scc])      = kreg0;
        *(bf16x8*)(&Ks[sr + 32][scc]) = kreg1;
        *(bf16x8*)(&Vt[sr][scc])      = vreg0;
        *(bf16x8*)(&Vt[sr + 32][scc]) = vreg1;
        if (tid < 64) kco[tid] = kcreg;
        __syncthreads();
        if (it + 1 < ktper) {
            const int k2 = kn + 64;
            kreg0 = *(const bf16x8*)(kbase + (size_t)(k2 + sr) * 1024 + scc);
            kreg1 = *(const bf16x8*)(kbase + (size_t)(k2 + sr + 32) * 1024 + scc);
            vreg0 = *(const bf16x8*)(vbase + (size_t)sr * Nseq + k2 + scc);
            vreg1 = *(const bf16x8*)(vbase + (size_t)(sr + 32) * Nseq + k2 + scc);
            if (tid < 64) kcreg = *(const float2*)(coords + (size_t)(b * Nseq + k2 + tid) * 2);
        }

        f32x4 sA[4];
#pragma unroll
        for (int am = 0; am < 4; ++am) {
            bf16x8 a0 = *(const bf16x8*)(&Ks[am * 16 + t][quad * 8]);
            bf16x8 a1 = *(const bf16x8*)(&Ks[am * 16 + t][32 + quad * 8]);
            f32x4 z = {};
            z = __builtin_amdgcn_mfma_f32_16x16x32_bf16(a0, bq0, z, 0, 0, 0);
            sA[am] = __builtin_amdgcn_mfma_f32_16x16x32_bf16(a1, bq1, z, 0, 0, 0);
        }

        float p[4][4];
#pragma unroll
        for (int am = 0; am < 4; ++am)
#pragma unroll
            for (int r = 0; r < 4; ++r) {
                float2 kc = kco[am * 16 + quad * 4 + r];
                float dx = qx - kc.x, dy = qy - kc.y;
                float dist = __builtin_amdgcn_sqrtf(dx * dx + dy * dy);
                float e = __builtin_amdgcn_exp2f(sA[am][r] * c1 - d1 * dist);
                p[am][r] = e;
                lrun += e;
            }

#pragma unroll
        for (int am = 0; am < 4; ++am) {
            bf16x4 pk;
#pragma unroll
            for (int r = 0; r < 4; ++r) pk[r] = (__bf16)p[am][r];
            *(bf16x4*)(&Ps[wave * 16 + t][am * 16 + quad * 4]) = pk;
        }

        bf16x8 ap0 = *(const bf16x8*)(&Ps[wave * 16 + t][quad * 8]);
        bf16x8 ap1 = *(const bf16x8*)(&Ps[wave * 16 + t][32 + quad * 8]);
#pragma unroll
        for (int ct = 0; ct < 4; ++ct) {
            bf16x8 bv0 = *(const bf16x8*)(&Vt[ct * 16 + t][quad * 8]);
            bf16x8 bv1 = *(const bf16x8*)(&Vt[ct * 16 + t][32 + quad * 8]);
            o[ct] = __builtin_amdgcn_mfma_f32_16x16x32_bf16(ap0, bv0, o[ct], 0, 0, 0);
            o[ct] = __builtin_amdgcn_mfma_f32_16x16x32_bf16(ap1, bv1, o[ct], 0, 0, 0);
        }
        kn += 64;
    }

    lrun += __shfl_xor(lrun, 16, 64);
    lrun += __shfl_xor(lrun, 32, 64);
    if (quad == 0)
        lp[(((size_t)s * Bdim + b) * Hn + h) * Nseq + qt * 64 + wave * 16 + t] = lrun;

    const int orow_base = qt * 64 + wave * 16 + quad * 4;
#pragma unroll
    for (int ct = 0; ct < 4; ++ct)
#pragma unroll
        for (int r = 0; r < 4; ++r) {
            size_t row = (size_t)s * ROWS + b * Nseq + orow_base + r;
            op[row * Dmod + h * DHd + ct * 16 + t] = (__bf16)o[ct][r];
        }
}

// ---------------- launch ----------------
extern "C" void kernel_launch(void* const* d_in, const int* in_sizes, int n_in,
                              void* d_out, int out_size, void* d_ws, size_t ws_size,
                              hipStream_t stream)
{
    (void)in_sizes; (void)n_in; (void)out_size; (void)ws_size;
    const float* x      = (const float*)d_in[0];
    const float* coords = (const float*)d_in[1];
    const float* q_w    = (const float*)d_in[2];
    const float* q_b    = (const float*)d_in[3];
    const float* k_w    = (const float*)d_in[4];
    const float* k_b    = (const float*)d_in[5];
    const float* v_w    = (const float*)d_in[6];
    const float* v_b    = (const float*)d_in[7];
    const float* o_w    = (const float*)d_in[8];
    const float* o_b    = (const float*)d_in[9];
    const float* gamma1 = (const float*)d_in[10];
    const float* ln1_w  = (const float*)d_in[11];
    const float* ln1_b  = (const float*)d_in[12];
    const float* fc1_w  = (const float*)d_in[13];
    const float* fc1_b  = (const float*)d_in[14];
    const float* fc2_w  = (const float*)d_in[15];
    const float* fc2_b  = (const float*)d_in[16];
    const float* gamma2 = (const float*)d_in[17];
    const float* ln2_w  = (const float*)d_in[18];
    const float* ln2_b  = (const float*)d_in[19];

    size_t off = 0;
    auto alloc = [&](size_t bytes) {
        void* p = (char*)d_ws + off;
        off += (bytes + 255) & ~(size_t)255;
        return p;
    };
    __bf16* wqkv  = (__bf16*)alloc((size_t)1536 * 512 * 2);
    __bf16* wo    = (__bf16*)alloc((size_t)512 * 512 * 2);
    __bf16* wfc1p = (__bf16*)alloc((size_t)NPACK * 512 * 2);
    __bf16* wfc2p = (__bf16*)alloc((size_t)512 * HC * 2);
    __bf16* xn    = (__bf16*)alloc((size_t)ROWS * Dmod * 2);
    __bf16* xn2   = (__bf16*)alloc((size_t)ROWS * Dmod * 2);
    __bf16* qkb   = (__bf16*)alloc((size_t)ROWS * 1024 * 2);
    __bf16* vtg   = (__bf16*)alloc((size_t)Bdim * Hn * DHd * Nseq * 2);
    __bf16* x1    = (__bf16*)alloc((size_t)ROWS * Dmod * 2);   // bf16 residual stream
    __bf16* hcomb = (__bf16*)alloc((size_t)ROWS * HC * 2);
    __bf16* opb   = (__bf16*)alloc((size_t)NSPLIT * ROWS * Dmod * 2);
    float*  lpb   = (float*)alloc((size_t)NSPLIT * Bdim * Hn * Nseq * 4);

    convert_ln<<<CONV_BLOCKS + ROWS, 256, 0, stream>>>(
        q_w, k_w, v_w, o_w, fc1_w, fc2_w, wqkv, wo, wfc1p, wfc2p,
        x, ln1_w, ln1_b, xn);

    qkv_gemm128<<<dim3(ROWS / 128, 12), 256, 0, stream>>>(xn, wqkv, q_b, k_b, v_b, qkb, vtg);

    attn_kernel<<<dim3(Nseq / 64, Hn, Bdim * NSPLIT), 256, 0, stream>>>(
        qkb, vtg, coords, opb, lpb, Nseq / 64 / NSPLIT);

    // O projection (+fused split-K merge) + residual1 -> x1 (bf16)
    gemm_res<0><<<dim3(ROWS / 64, Dmod / 64), 512, 0, stream>>>(
        nullptr, Dmod, opb, lpb, wo, Dmod, o_b, Dmod, (void*)x1, (const void*)x, gamma1);

    ln_kernel_bf16<<<ROWS, 256, 0, stream>>>(x1, ln2_w, ln2_b, xn2);

    fc1_gemm128<<<dim3(ROWS / 128, NPACK / 128), 256, 0, stream>>>(xn2, wfc1p, fc1_b, hcomb);

    // fc2 + residual2 -> d_out (fp32)
    gemm_res<1><<<dim3(ROWS / 64, Dmod / 64), 512, 0, stream>>>(
        hcomb, HC, nullptr, nullptr, wfc2p, HC, fc2_b, HC, d_out, (const void*)x1, gamma2);
}